// Round 8
// baseline (185.159 us; speedup 1.0000x reference)
//
#include <hip/hip_runtime.h>
#include <hip/hip_bf16.h>

#define NROWS 8192
#define DIM   512
#define KSEL  20
#define NSURV 384
#define NTRI  2080   // 64*65/2 lower-triangle 128x128 tiles

typedef unsigned int u32;
typedef unsigned long long u64;
typedef short bf16x8 __attribute__((ext_vector_type(8)));
typedef float f32x4 __attribute__((ext_vector_type(4)));
typedef ushort u16x2 __attribute__((ext_vector_type(2)));

typedef const void __attribute__((address_space(1))) as1_void;
typedef void __attribute__((address_space(3))) as3_void;

__device__ __forceinline__ void async_ld16(const ushort* g, ushort* l) {
    __builtin_amdgcn_global_load_lds((as1_void*)g, (as3_void*)l, 16, 0, 0);
}

// round-to-nearest-even f32 -> bf16 bits
__device__ __forceinline__ ushort f2bf(float f) {
    u32 u = __float_as_uint(f);
    return (ushort)((u + 0x7FFFu + ((u >> 16) & 1u)) >> 16);
}

// monotone map: integer compare == float compare (u16 bf16 pattern)
__device__ __forceinline__ u32 mono16(u32 r) {
    return r ^ (0x8000u | ((r >> 15) * 0x7FFFu));
}
// packed both-halves monotone map
__device__ __forceinline__ u32 mono2(u32 w) {
    return w ^ (0x80008000u | (((w >> 15) & 0x10001u) * 0x7FFFu));
}
__device__ __forceinline__ u32 mkey(float f) { return mono16((u32)f2bf(f)); }

__device__ __forceinline__ u32 pkmax(u32 a, u32 b) {
    union { u32 u; u16x2 v; } x, y; x.u = a; y.u = b;
    x.v = __builtin_elementwise_max(x.v, y.v);
    return x.u;
}
__device__ __forceinline__ u32 pkmin(u32 a, u32 b) {
    union { u32 u; u16x2 v; } x, y; x.u = a; y.u = b;
    x.v = __builtin_elementwise_min(x.v, y.v);
    return x.u;
}

// lower-triangle block index -> (by, bx), bx <= by
__device__ __forceinline__ void tri_idx(int t, int& by, int& bx) {
    by = (int)((sqrtf(8.0f * (float)t + 1.0f) - 1.0f) * 0.5f);
    while ((by + 1) * (by + 2) / 2 <= t) ++by;
    while (by * (by + 1) / 2 > t) --by;
    bx = t - by * (by + 1) / 2;
}

// ---------------- normalize: fp32 rows -> unit-norm bf16 rows ----------------
__global__ __launch_bounds__(256) void k_norm(const float* __restrict__ x,
                                              ushort* __restrict__ xn) {
    int lane = threadIdx.x & 63;
    int wv   = threadIdx.x >> 6;
    int row  = blockIdx.x * 4 + wv;
    const float4* xr = (const float4*)(x + (size_t)row * DIM);
    float4 a = xr[2 * lane];
    float4 b = xr[2 * lane + 1];
    float ss = a.x*a.x + a.y*a.y + a.z*a.z + a.w*a.w
             + b.x*b.x + b.y*b.y + b.z*b.z + b.w*b.w;
    #pragma unroll
    for (int off = 32; off; off >>= 1) ss += __shfl_xor(ss, off);
    float sc = 1.0f / fmaxf(sqrtf(ss), 1e-12f);
    float v[8] = {a.x*sc, a.y*sc, a.z*sc, a.w*sc, b.x*sc, b.y*sc, b.z*sc, b.w*sc};
    union { ushort u[8]; uint4 q; } o;
    #pragma unroll
    for (int i = 0; i < 8; ++i) o.u[i] = f2bf(v[i]);
    *(uint4*)(xn + (size_t)row * DIM + lane * 8) = o.q;
}

// ---------------- GEMM: lower-triangle tiles of C = Xn*Xn^T, diag=-3 ---------
// 128x128 tile, 4 waves (2x2), 4x4 subtiles of 16x16x32 bf16 MFMA each.
// Writes ONLY the 2080 lower tiles (row-major, via LDS bounce) + the M digest
// (per-(row,64-col-seg) maxima; row-digest covers segs bx*2+wc, col-digest of
// off-diag tiles covers the mirrored segs by*2+wr). Upper C never exists.
__global__ __launch_bounds__(256) void k_gemm(const ushort* __restrict__ xn,
                                              ushort* __restrict__ C,
                                              ushort* __restrict__ M) {
    __shared__ ushort sh[128 * 128];         // K-loop: A|B staging; epi: tile
    ushort* lA = sh;
    ushort* lB = sh + 128 * 64;
    int tid  = threadIdx.x;
    int lane = tid & 63, wv = tid >> 6;
    int wr = wv >> 1, wc = wv & 1;
    int q = lane >> 4, m = lane & 15;
    int bx, by;
    tri_idx(blockIdx.x, by, bx);
    int grow0 = by * 128;          // A rows (global)
    int gcol0 = bx * 128;          // B rows = C cols (global)
    f32x4 acc[4][4] = {};

    int lr = lane >> 3;   // row within 8-row group
    int lc = lane & 7;    // LDS chunk slot this lane fills
    for (int kc = 0; kc < 8; ++kc) {
        #pragma unroll
        for (int t = 0; t < 4; ++t) {
            int rb  = wv * 32 + t * 8;     // wave-uniform row base
            int r   = rb + lr;
            int fch = lc ^ (r & 7);        // XOR chunk swizzle (conflict-free)
            async_ld16(xn + (size_t)(grow0 + r) * DIM + kc * 64 + fch * 8, &lA[rb * 64]);
            async_ld16(xn + (size_t)(gcol0 + r) * DIM + kc * 64 + fch * 8, &lB[rb * 64]);
        }
        __syncthreads();
        #pragma unroll
        for (int s = 0; s < 2; ++s) {
            bf16x8 af[4], bfr[4];
            #pragma unroll
            for (int i = 0; i < 4; ++i) {
                int ra = wr * 64 + i * 16 + m;
                af[i]  = *(const bf16x8*)&lA[ra * 64 + (((s * 4 + q) ^ (ra & 7)) * 8)];
                int rb2 = wc * 64 + i * 16 + m;
                bfr[i] = *(const bf16x8*)&lB[rb2 * 64 + (((s * 4 + q) ^ (rb2 & 7)) * 8)];
            }
            #pragma unroll
            for (int i = 0; i < 4; ++i)
                #pragma unroll
                for (int j = 0; j < 4; ++j)
                    acc[i][j] = __builtin_amdgcn_mfma_f32_16x16x32_bf16(af[i], bfr[j], acc[i][j], 0, 0, 0);
        }
        __syncthreads();
    }

    // ---- epilogue phase 1: stage row-tile into LDS + M digest ----
    // C/D layout: col=lane&15, row=quad*4+reg (m89/m91-verified).
    // LDS dword swizzle D = r*64 + ((cl>>1) ^ (q(r)<<3)), q(r)=(r>>2)&3:
    // scalar writes 2-way max; b128 row readback contiguous, 2-way max.
    float cmf[4] = {-3.0f, -3.0f, -3.0f, -3.0f};     // per-j col maxima
    #pragma unroll
    for (int i = 0; i < 4; ++i) {
        float rmf[4] = {-3.0f, -3.0f, -3.0f, -3.0f}; // per-reg row maxima
        int rloc = wr * 64 + i * 16 + q * 4;         // local row base (0..127)
        #pragma unroll
        for (int j = 0; j < 4; ++j) {
            int cl = wc * 64 + j * 16 + m;           // local col
            int c  = gcol0 + cl;                     // global col
            #pragma unroll
            for (int reg = 0; reg < 4; ++reg) {
                int r    = rloc + reg;
                int grw  = grow0 + r;
                float a  = acc[i][j][reg];
                bool dg  = (grw == c);
                float mv = dg ? -3.0f : a;
                rmf[reg] = fmaxf(rmf[reg], mv);
                cmf[j]   = fmaxf(cmf[j], mv);
                int D = r * 64 + ((cl >> 1) ^ (q << 3));
                sh[D * 2 + (cl & 1)] = dg ? (ushort)0xC040 : f2bf(a);
            }
        }
        // row maxima: packed 2-rows/u32, reduce over 16 lanes (m) of each quad
        u32 p01 = mkey(rmf[0]) | (mkey(rmf[1]) << 16);
        u32 p23 = mkey(rmf[2]) | (mkey(rmf[3]) << 16);
        #pragma unroll
        for (int off = 1; off <= 8; off <<= 1) {
            p01 = pkmax(p01, (u32)__shfl_xor((int)p01, off));
            p23 = pkmax(p23, (u32)__shfl_xor((int)p23, off));
        }
        if (m == 0) {
            size_t mb = (size_t)(grow0 + rloc) * 128 + bx * 2 + wc;
            M[mb]       = (ushort)(p01 & 0xFFFFu);
            M[mb + 128] = (ushort)(p01 >> 16);
            M[mb + 256] = (ushort)(p23 & 0xFFFFu);
            M[mb + 384] = (ushort)(p23 >> 16);
        }
    }
    if (bx != by) {
        // col maxima (mirror rows): packed 2-cols/u32, reduce over quads (q)
        u32 q01 = mkey(cmf[0]) | (mkey(cmf[1]) << 16);
        u32 q23 = mkey(cmf[2]) | (mkey(cmf[3]) << 16);
        q01 = pkmax(q01, (u32)__shfl_xor((int)q01, 16));
        q01 = pkmax(q01, (u32)__shfl_xor((int)q01, 32));
        q23 = pkmax(q23, (u32)__shfl_xor((int)q23, 16));
        q23 = pkmax(q23, (u32)__shfl_xor((int)q23, 32));
        if (q == 0) {
            int gc = gcol0 + wc * 64 + m;
            int sg = by * 2 + wr;
            M[(size_t)(gc +  0) * 128 + sg] = (ushort)(q01 & 0xFFFFu);
            M[(size_t)(gc + 16) * 128 + sg] = (ushort)(q01 >> 16);
            M[(size_t)(gc + 32) * 128 + sg] = (ushort)(q23 & 0xFFFFu);
            M[(size_t)(gc + 48) * 128 + sg] = (ushort)(q23 >> 16);
        }
    }
    __syncthreads();

    // ---- epilogue phase 2: coalesced row-major readback & store ----
    int tr = tid >> 4;       // 0..15
    int tc = tid & 15;       // 8-col chunk
    #pragma unroll
    for (int p = 0; p < 8; ++p) {
        int r  = p * 16 + tr;
        int qr = (r >> 2) & 3;
        uint4 v = *(const uint4*)&sh[(r * 64 + ((tc * 4) ^ (qr << 3))) * 2];
        *(uint4*)&C[(size_t)(by * 128 + r) * NROWS + gcol0 + tc * 8] = v;
    }
}

// ---------------- thresh: exact per-row T = 20th-largest seg-max -------------
__global__ __launch_bounds__(256) void k_thresh(const ushort* __restrict__ M,
                                                ushort* __restrict__ T) {
    int lane = threadIdx.x & 63;
    int wv   = threadIdx.x >> 6;
    int row  = blockIdx.x * 4 + wv;
    u32 pm  = *(const u32*)&M[(size_t)row * 128 + 2 * lane];
    u32 klo = pm & 0xFFFFu, khi = pm >> 16;
    u32 Tv = 0;
    #pragma unroll
    for (int b = 15; b >= 0; --b) {
        u32 cand = Tv | (1u << b);
        int c = __popcll(__ballot(klo >= cand)) + __popcll(__ballot(khi >= cand));
        if (c >= KSEL) Tv = cand;
    }
    if (Tv == 0) Tv = 1;
    if (lane == 0) T[row] = (ushort)Tv;
}

// ---------------- scan: stream lower tiles, append survivors ----------------
// Coalesced sweep of the 66 MB lower triangle (L3-warm). Each physical element
// (r,c) of an off-diag tile is a candidate for row r (col c) and row c (col r);
// diag-tile elements are candidates for their own row only. Survivors (key|col)
// append to per-row lists via one global atomic each (~37/row total).
__global__ __launch_bounds__(256) void k_scan(const ushort* __restrict__ C,
                                              const ushort* __restrict__ T,
                                              u32* __restrict__ lists,
                                              u32* __restrict__ cnts) {
    int by, bx;
    tri_idx(blockIdx.x, by, bx);
    int tid = threadIdx.x;
    int tr  = tid >> 4;
    int gc  = bx * 128 + (tid & 15) * 8;
    bool diag = (bx == by);
    uint4 tq = *(const uint4*)&T[gc];            // mirror thresholds (8 cols)
    u32 ts[4] = { tq.x, tq.y, tq.z, tq.w };
    u32 pmn = pkmin(pkmin(ts[0], ts[1]), pkmin(ts[2], ts[3]));
    u32 tmn = min(pmn & 0xFFFFu, pmn >> 16);
    #pragma unroll
    for (int p = 0; p < 8; ++p) {
        int gr = by * 128 + p * 16 + tr;
        uint4 v = *(const uint4*)&C[(size_t)gr * NROWS + gc];
        u32 k0 = mono2(v.x), k1 = mono2(v.y), k2 = mono2(v.z), k3 = mono2(v.w);
        u32 pmx = pkmax(pkmax(k0, k1), pkmax(k2, k3));
        u32 mx  = max(pmx & 0xFFFFu, pmx >> 16);
        u32 Tr  = (u32)T[gr];
        u32 ks[4] = { k0, k1, k2, k3 };
        if (mx >= Tr) {                          // row-orientation candidates
            #pragma unroll
            for (int h = 0; h < 4; ++h) {
                u32 kA = ks[h] & 0xFFFFu, kB = ks[h] >> 16;
                if (kA >= Tr) { u32 o = atomicAdd(&cnts[gr], 1u); if (o < NSURV) lists[(size_t)gr * NSURV + o] = (kA << 16) | (u32)(gc + 2 * h); }
                if (kB >= Tr) { u32 o = atomicAdd(&cnts[gr], 1u); if (o < NSURV) lists[(size_t)gr * NSURV + o] = (kB << 16) | (u32)(gc + 2 * h + 1); }
            }
        }
        if (!diag && mx >= tmn) {                // mirror-orientation candidates
            #pragma unroll
            for (int h = 0; h < 4; ++h) {
                u32 kA = ks[h] & 0xFFFFu, kB = ks[h] >> 16;
                u32 tA = ts[h] & 0xFFFFu, tB = ts[h] >> 16;
                int cA = gc + 2 * h, cB = cA + 1;
                if (kA >= tA) { u32 o = atomicAdd(&cnts[cA], 1u); if (o < NSURV) lists[(size_t)cA * NSURV + o] = (kA << 16) | (u32)gr; }
                if (kB >= tB) { u32 o = atomicAdd(&cnts[cB], 1u); if (o < NSURV) lists[(size_t)cB * NSURV + o] = (kB << 16) | (u32)gr; }
            }
        }
    }
}

// ---------------- topk: exact top-20 + BCE from per-row candidate list ------
__global__ __launch_bounds__(256) void k_topk(const u32* __restrict__ lists,
                                              const u32* __restrict__ cnts,
                                              const int* __restrict__ labels,
                                              float* __restrict__ partials) {
    int lane = threadIdx.x & 63;
    int wv   = threadIdx.x >> 6;
    int row  = blockIdx.x * 4 + wv;
    u32 cnt = min(cnts[row], (u32)NSURV);
    const u32* L = lists + (size_t)row * NSURV;
    int mylab = labels[row];
    float loss = 0.0f;

    if (cnt <= 64u) {
        // fast path: one survivor per lane; V20 bsearch = 16 ballots
        u32 gg  = ((u32)lane < cnt) ? L[lane] : 0u;
        u32 key = gg >> 16;
        u32 V = 0;
        #pragma unroll
        for (int b = 15; b >= 0; --b) {
            u32 cand = V | (1u << b);
            if (__popcll(__ballot(key >= cand)) >= KSEL) V = cand;
        }
        int cgt  = __popcll(__ballot(key > V));
        int ceq  = __popcll(__ballot(gg != 0 && key == V));
        int need = KSEL - cgt;
        bool incl;
        if (ceq == need) {
            incl = (gg != 0) && (key >= V);
        } else {
            // more ties than slots: take `need` largest cols among ties
            u32 col = gg & 0xFFFFu;
            bool tie = (gg != 0) && (key == V);
            u32 Cv = 0;
            #pragma unroll
            for (int b = 15; b >= 0; --b) {
                u32 cand2 = Cv | (1u << b);
                if (__popcll(__ballot(tie && col >= cand2)) >= need) Cv = cand2;
            }
            incl = (key > V) || (tie && col >= Cv);   // cols unique -> exact
        }
        if (incl) {
            u32 col = gg & 0xFFFFu;
            u32 raw = (key & 0x8000u) ? (key ^ 0x8000u) : (key ^ 0xFFFFu);
            float v = __uint_as_float(raw << 16);
            float p = (v + 1.0f) * 0.5f;
            bool tm = (labels[col] == mylab);
            loss -= tm ? fmaxf(logf(p), -100.0f) : fmaxf(log1pf(-p), -100.0f);
        }
    } else {
        // fallback (rare): up to 6 survivors per lane
        u32 g[6];
        #pragma unroll
        for (int j = 0; j < 6; ++j) {
            u32 idx = (u32)lane + (u32)j * 64u;
            g[j] = (idx < cnt) ? L[idx] : 0u;
        }
        u32 V = 0;
        #pragma unroll
        for (int b = 15; b >= 0; --b) {
            u32 cand = V | (1u << b);
            int c = 0;
            #pragma unroll
            for (int j = 0; j < 6; ++j)
                c += __popcll(__ballot((g[j] >> 16) >= cand));
            if (c >= KSEL) V = cand;
        }
        int cgt = 0, ceq = 0;
        #pragma unroll
        for (int j = 0; j < 6; ++j) {
            cgt += __popcll(__ballot(g[j] != 0 && (g[j] >> 16) > V));
            ceq += __popcll(__ballot(g[j] != 0 && (g[j] >> 16) == V));
        }
        int need = KSEL - cgt;
        bool all_ties = (ceq == need);
        #pragma unroll
        for (int j = 0; j < 6; ++j) {
            u32 key = g[j] >> 16, col = g[j] & 0xFFFFu;
            if (g[j] != 0 && (key > V || (all_ties && key == V))) {
                u32 raw = (key & 0x8000u) ? (key ^ 0x8000u) : (key ^ 0xFFFFu);
                float v = __uint_as_float(raw << 16);
                float p = (v + 1.0f) * 0.5f;
                bool tm = (labels[col] == mylab);
                loss -= tm ? fmaxf(logf(p), -100.0f) : fmaxf(log1pf(-p), -100.0f);
            }
        }
        if (!all_ties) {
            for (int r = 0; r < need; ++r) {
                u32 best = 0;
                #pragma unroll
                for (int j = 0; j < 6; ++j) {
                    u32 c2 = (g[j] != 0 && (g[j] >> 16) == V) ? ((g[j] & 0xFFFFu) + 1u) : 0u;
                    best = max(best, c2);
                }
                #pragma unroll
                for (int off = 32; off; off >>= 1) best = max(best, (u32)__shfl_xor((int)best, off));
                #pragma unroll
                for (int j = 0; j < 6; ++j) {
                    if (g[j] != 0 && (g[j] >> 16) == V && ((g[j] & 0xFFFFu) + 1u) == best) {
                        u32 col = g[j] & 0xFFFFu;
                        u32 raw = (V & 0x8000u) ? (V ^ 0x8000u) : (V ^ 0xFFFFu);
                        float v = __uint_as_float(raw << 16);
                        float p = (v + 1.0f) * 0.5f;
                        bool tm = (labels[col] == mylab);
                        loss -= tm ? fmaxf(logf(p), -100.0f) : fmaxf(log1pf(-p), -100.0f);
                        g[j] = 0;
                    }
                }
            }
        }
    }

    #pragma unroll
    for (int off = 32; off; off >>= 1) loss += __shfl_xor(loss, off);
    if (lane == 0) partials[row] = loss;
}

__global__ __launch_bounds__(256) void k_final(const float* __restrict__ partials,
                                               float* __restrict__ out) {
    __shared__ float s[4];
    int tid = threadIdx.x, lane = tid & 63, wvi = tid >> 6;
    const float4* p4 = (const float4*)partials;
    float sum = 0.0f;
    #pragma unroll
    for (int i = 0; i < 8; ++i) {
        float4 v = p4[tid + i * 256];
        sum += v.x + v.y + v.z + v.w;
    }
    #pragma unroll
    for (int off = 32; off; off >>= 1) sum += __shfl_xor(sum, off);
    if (lane == 0) s[wvi] = sum;
    __syncthreads();
    if (tid == 0) out[0] = (s[0] + s[1] + s[2] + s[3]) * (1.0f / (float)(NROWS * KSEL));
}

extern "C" void kernel_launch(void* const* d_in, const int* in_sizes, int n_in,
                              void* d_out, int out_size, void* d_ws, size_t ws_size,
                              hipStream_t stream) {
    const float* batch  = (const float*)d_in[0];
    const int*   labels = (const int*)d_in[1];

    ushort* xn = (ushort*)d_ws;                 // 8 MB
    ushort* C  = xn + (size_t)NROWS * DIM;      // 128 MB (lower tiles only used)

    // Scratch carved from the batch input buffer (16 MB), all written only
    // after k_norm has fully consumed batch (stream-ordered):
    // [0,2M) M digest | [2M,+16K) T | [+64K,+32K) cnts | [+128K,+32K) partials
    // [4M,16M) lists (8192 rows x 384 x u32)
    char* scr = (char*)d_in[0];
    ushort* M        = (ushort*)scr;
    ushort* T        = (ushort*)(scr + (2u << 20));
    u32*    cnts     = (u32*)  (scr + (2u << 20) + (64u << 10));
    float*  partials = (float*)(scr + (2u << 20) + (128u << 10));
    u32*    lists    = (u32*)  (scr + (4u << 20));

    k_norm<<<NROWS / 4, 256, 0, stream>>>(batch, xn);
    hipMemsetAsync(cnts, 0, NROWS * sizeof(u32), stream);
    k_gemm  <<<NTRI,      256, 0, stream>>>(xn, C, M);
    k_thresh<<<NROWS / 4, 256, 0, stream>>>(M, T);
    k_scan  <<<NTRI,      256, 0, stream>>>(C, T, lists, cnts);
    k_topk  <<<NROWS / 4, 256, 0, stream>>>(lists, cnts, labels, partials);
    k_final <<<1,         256, 0, stream>>>(partials, (float*)d_out);
}

// Round 9
// 177.467 us; speedup vs baseline: 1.0433x; 1.0433x over previous
//
#include <hip/hip_runtime.h>
#include <hip/hip_bf16.h>

#define NROWS 8192
#define DIM   512
#define KSEL  20
#define NSURV 384
#define NTRI  2080   // 64*65/2 lower-triangle 128x128 tiles

typedef unsigned int u32;
typedef unsigned long long u64;
typedef short bf16x8 __attribute__((ext_vector_type(8)));
typedef float f32x4 __attribute__((ext_vector_type(4)));
typedef ushort u16x2 __attribute__((ext_vector_type(2)));

typedef const void __attribute__((address_space(1))) as1_void;
typedef void __attribute__((address_space(3))) as3_void;

__device__ __forceinline__ void async_ld16(const ushort* g, ushort* l) {
    __builtin_amdgcn_global_load_lds((as1_void*)g, (as3_void*)l, 16, 0, 0);
}

// round-to-nearest-even f32 -> bf16 bits
__device__ __forceinline__ ushort f2bf(float f) {
    u32 u = __float_as_uint(f);
    return (ushort)((u + 0x7FFFu + ((u >> 16) & 1u)) >> 16);
}

// monotone map: integer compare == float compare (u16 bf16 pattern)
__device__ __forceinline__ u32 mono16(u32 r) {
    return r ^ (0x8000u | ((r >> 15) * 0x7FFFu));
}
// packed both-halves monotone map
__device__ __forceinline__ u32 mono2(u32 w) {
    return w ^ (0x80008000u | (((w >> 15) & 0x10001u) * 0x7FFFu));
}
__device__ __forceinline__ u32 mkey(float f) { return mono16((u32)f2bf(f)); }

__device__ __forceinline__ u32 pkmax(u32 a, u32 b) {
    union { u32 u; u16x2 v; } x, y; x.u = a; y.u = b;
    x.v = __builtin_elementwise_max(x.v, y.v);
    return x.u;
}
__device__ __forceinline__ u32 pkmin(u32 a, u32 b) {
    union { u32 u; u16x2 v; } x, y; x.u = a; y.u = b;
    x.v = __builtin_elementwise_min(x.v, y.v);
    return x.u;
}

// lower-triangle block index -> (by, bx), bx <= by
__device__ __forceinline__ void tri_idx(int t, int& by, int& bx) {
    by = (int)((sqrtf(8.0f * (float)t + 1.0f) - 1.0f) * 0.5f);
    while ((by + 1) * (by + 2) / 2 <= t) ++by;
    while (by * (by + 1) / 2 > t) --by;
    bx = t - by * (by + 1) / 2;
}

__device__ __forceinline__ void append(u32* lists, u32* cnts, int row, u32 val) {
    u32 o = atomicAdd(&cnts[row], 1u);
    if (o < NSURV) lists[(size_t)row * NSURV + o] = val;
}

// ---------------- normalize: fp32 rows -> unit-norm bf16 rows ----------------
__global__ __launch_bounds__(256) void k_norm(const float* __restrict__ x,
                                              ushort* __restrict__ xn) {
    int lane = threadIdx.x & 63;
    int wv   = threadIdx.x >> 6;
    int row  = blockIdx.x * 4 + wv;
    const float4* xr = (const float4*)(x + (size_t)row * DIM);
    float4 a = xr[2 * lane];
    float4 b = xr[2 * lane + 1];
    float ss = a.x*a.x + a.y*a.y + a.z*a.z + a.w*a.w
             + b.x*b.x + b.y*b.y + b.z*b.z + b.w*b.w;
    #pragma unroll
    for (int off = 32; off; off >>= 1) ss += __shfl_xor(ss, off);
    float sc = 1.0f / fmaxf(sqrtf(ss), 1e-12f);
    float v[8] = {a.x*sc, a.y*sc, a.z*sc, a.w*sc, b.x*sc, b.y*sc, b.z*sc, b.w*sc};
    union { ushort u[8]; uint4 q; } o;
    #pragma unroll
    for (int i = 0; i < 8; ++i) o.u[i] = f2bf(v[i]);
    *(uint4*)(xn + (size_t)row * DIM + lane * 8) = o.q;
}

// ---------------- GEMM: lower-triangle tiles of C = Xn*Xn^T, diag=-3 ---------
// 128x128 tile, 4 waves (2x2), 4x4 subtiles of 16x16x32 bf16 MFMA each.
// C is TILE-MAJOR in MFMA-permuted order: tile t occupies C[t*16384 ..);
// element index e = ((wv*16+i*4+j)*64 + lane)*4 + reg maps to local
// row = (wv>>1)*64+i*16+(lane>>4)*4+reg, col = (wv&1)*64+j*16+(lane&15).
// Each lane stores 4 packed bf16 per subtile as one 8B uint2 (512B/wave-store,
// whole tile contiguous) -> no LDS bounce, no extra barriers.
// Also emits the M digest (per-(row,64-col-seg) maxima as monotone-u16 keys).
__global__ __launch_bounds__(256) void k_gemm(const ushort* __restrict__ xn,
                                              ushort* __restrict__ C,
                                              ushort* __restrict__ M) {
    __shared__ ushort sh[2 * 128 * 64];
    ushort* lA = sh;
    ushort* lB = sh + 128 * 64;
    int tid  = threadIdx.x;
    int lane = tid & 63, wv = tid >> 6;
    int wr = wv >> 1, wc = wv & 1;
    int q = lane >> 4, m = lane & 15;
    int bx, by;
    tri_idx(blockIdx.x, by, bx);
    int grow0 = by * 128;          // A rows (global)
    int gcol0 = bx * 128;          // B rows = C cols (global)
    f32x4 acc[4][4] = {};

    int lr = lane >> 3;   // row within 8-row group
    int lc = lane & 7;    // LDS chunk slot this lane fills
    for (int kc = 0; kc < 8; ++kc) {
        #pragma unroll
        for (int t = 0; t < 4; ++t) {
            int rb  = wv * 32 + t * 8;     // wave-uniform row base
            int r   = rb + lr;
            int fch = lc ^ (r & 7);        // XOR chunk swizzle (conflict-free)
            async_ld16(xn + (size_t)(grow0 + r) * DIM + kc * 64 + fch * 8, &lA[rb * 64]);
            async_ld16(xn + (size_t)(gcol0 + r) * DIM + kc * 64 + fch * 8, &lB[rb * 64]);
        }
        __syncthreads();
        #pragma unroll
        for (int s = 0; s < 2; ++s) {
            bf16x8 af[4], bfr[4];
            #pragma unroll
            for (int i = 0; i < 4; ++i) {
                int ra = wr * 64 + i * 16 + m;
                af[i]  = *(const bf16x8*)&lA[ra * 64 + (((s * 4 + q) ^ (ra & 7)) * 8)];
                int rb2 = wc * 64 + i * 16 + m;
                bfr[i] = *(const bf16x8*)&lB[rb2 * 64 + (((s * 4 + q) ^ (rb2 & 7)) * 8)];
            }
            #pragma unroll
            for (int i = 0; i < 4; ++i)
                #pragma unroll
                for (int j = 0; j < 4; ++j)
                    acc[i][j] = __builtin_amdgcn_mfma_f32_16x16x32_bf16(af[i], bfr[j], acc[i][j], 0, 0, 0);
        }
        __syncthreads();
    }

    // ---- epilogue: direct permuted tile store + M digest ----
    // C/D layout: col=lane&15, row=quad*4+reg (m89/m91-verified)
    size_t tb = (size_t)blockIdx.x * 16384;
    float cmf[4] = {-3.0f, -3.0f, -3.0f, -3.0f};     // per-j col maxima
    #pragma unroll
    for (int i = 0; i < 4; ++i) {
        float rmf[4] = {-3.0f, -3.0f, -3.0f, -3.0f}; // per-reg row maxima
        int rloc = wr * 64 + i * 16 + q * 4;         // local row base (0..127)
        #pragma unroll
        for (int j = 0; j < 4; ++j) {
            int cl = wc * 64 + j * 16 + m;           // local col
            int c  = gcol0 + cl;                     // global col
            ushort sv[4];
            #pragma unroll
            for (int reg = 0; reg < 4; ++reg) {
                int grw  = grow0 + rloc + reg;
                float a  = acc[i][j][reg];
                bool dg  = (grw == c);
                float mv = dg ? -3.0f : a;
                rmf[reg] = fmaxf(rmf[reg], mv);
                cmf[j]   = fmaxf(cmf[j], mv);
                sv[reg]  = dg ? (ushort)0xC040 : f2bf(a);
            }
            uint2 o = { (u32)sv[0] | ((u32)sv[1] << 16),
                        (u32)sv[2] | ((u32)sv[3] << 16) };
            *(uint2*)&C[tb + (size_t)(((wv * 16 + i * 4 + j) * 64) + lane) * 4] = o;
        }
        // row maxima: packed 2-rows/u32, reduce over 16 lanes (m) of each quad
        u32 p01 = mkey(rmf[0]) | (mkey(rmf[1]) << 16);
        u32 p23 = mkey(rmf[2]) | (mkey(rmf[3]) << 16);
        #pragma unroll
        for (int off = 1; off <= 8; off <<= 1) {
            p01 = pkmax(p01, (u32)__shfl_xor((int)p01, off));
            p23 = pkmax(p23, (u32)__shfl_xor((int)p23, off));
        }
        if (m == 0) {
            size_t mb = (size_t)(grow0 + rloc) * 128 + bx * 2 + wc;
            M[mb]       = (ushort)(p01 & 0xFFFFu);
            M[mb + 128] = (ushort)(p01 >> 16);
            M[mb + 256] = (ushort)(p23 & 0xFFFFu);
            M[mb + 384] = (ushort)(p23 >> 16);
        }
    }
    if (bx != by) {
        // col maxima (mirror rows): packed 2-cols/u32, reduce over quads (q)
        u32 q01 = mkey(cmf[0]) | (mkey(cmf[1]) << 16);
        u32 q23 = mkey(cmf[2]) | (mkey(cmf[3]) << 16);
        q01 = pkmax(q01, (u32)__shfl_xor((int)q01, 16));
        q01 = pkmax(q01, (u32)__shfl_xor((int)q01, 32));
        q23 = pkmax(q23, (u32)__shfl_xor((int)q23, 16));
        q23 = pkmax(q23, (u32)__shfl_xor((int)q23, 32));
        if (q == 0) {
            int gc = gcol0 + wc * 64 + m;
            int sg = by * 2 + wr;
            M[(size_t)(gc +  0) * 128 + sg] = (ushort)(q01 & 0xFFFFu);
            M[(size_t)(gc + 16) * 128 + sg] = (ushort)(q01 >> 16);
            M[(size_t)(gc + 32) * 128 + sg] = (ushort)(q23 & 0xFFFFu);
            M[(size_t)(gc + 48) * 128 + sg] = (ushort)(q23 >> 16);
        }
    }
}

// ---------------- thresh: exact per-row T = 20th-largest seg-max -------------
__global__ __launch_bounds__(256) void k_thresh(const ushort* __restrict__ M,
                                                ushort* __restrict__ T) {
    int lane = threadIdx.x & 63;
    int wv   = threadIdx.x >> 6;
    int row  = blockIdx.x * 4 + wv;
    u32 pm  = *(const u32*)&M[(size_t)row * 128 + 2 * lane];
    u32 klo = pm & 0xFFFFu, khi = pm >> 16;
    u32 Tv = 0;
    #pragma unroll
    for (int b = 15; b >= 0; --b) {
        u32 cand = Tv | (1u << b);
        int c = __popcll(__ballot(klo >= cand)) + __popcll(__ballot(khi >= cand));
        if (c >= KSEL) Tv = cand;
    }
    if (Tv == 0) Tv = 1;
    if (lane == 0) T[row] = (ushort)Tv;
}

// ---------------- scan: sequential sweep of tile-major C --------------------
// Thread tid reads tile[s*2048 + tid*8] -> perfectly coalesced 1KB/wave-instr
// over the whole 66MB (L3-warm). Each uint4 = 4 consecutive rows x 2 cols of
// the tile (MFMA-permuted layout decode). Row thresholds load as one packed
// uint2 of T matching the key halves; col thresholds as one u32.
__global__ __launch_bounds__(256) void k_scan(const ushort* __restrict__ C,
                                              const ushort* __restrict__ T,
                                              u32* __restrict__ lists,
                                              u32* __restrict__ cnts) {
    int by, bx;
    tri_idx(blockIdx.x, by, bx);
    const ushort* tile = C + (size_t)blockIdx.x * 16384;
    int tid = threadIdx.x;
    bool diag = (bx == by);
    #pragma unroll
    for (int s = 0; s < 8; ++s) {
        int e0 = s * 2048 + tid * 8;
        uint4 v = *(const uint4*)&tile[e0];
        int sub   = e0 >> 8;                  // (wv*16 + i*4 + j)
        int wv2   = sub >> 4, ii = (sub >> 2) & 3, jj = sub & 3;
        int lane0 = (e0 >> 2) & 63;           // even
        int qq = lane0 >> 4, m0 = lane0 & 15;
        int gr0 = by * 128 + (wv2 >> 1) * 64 + ii * 16 + qq * 4;  // rows gr0..+3
        int gc0 = bx * 128 + (wv2 & 1) * 64 + jj * 16 + m0;       // cols gc0,+1
        uint2 trw = *(const uint2*)&T[gr0];   // packed row thresholds
        u32   tc2 = *(const u32*)&T[gc0];     // col thresholds (lo,hi)
        u32 k0 = mono2(v.x), k1 = mono2(v.y), k2 = mono2(v.z), k3 = mono2(v.w);
        u32 pmx = pkmax(pkmax(k0, k1), pkmax(k2, k3));
        u32 mx  = max(pmx & 0xFFFFu, pmx >> 16);
        u32 rm2 = pkmin(trw.x, trw.y);
        u32 rmn = min(rm2 & 0xFFFFu, rm2 >> 16);
        u32 cmn = min(tc2 & 0xFFFFu, tc2 >> 16);
        u32 thr = diag ? rmn : min(rmn, cmn);
        if (mx < thr) continue;
        u32 ks[4]  = { k0, k1, k2, k3 };
        u32 trs[4] = { trw.x, trw.y, trw.x, trw.y };
        u32 tcs[4] = { tc2 & 0xFFFFu, tc2 & 0xFFFFu, tc2 >> 16, tc2 >> 16 };
        int cls[4] = { gc0, gc0, gc0 + 1, gc0 + 1 };
        int rws[4] = { gr0, gr0 + 2, gr0, gr0 + 2 };
        #pragma unroll
        for (int h = 0; h < 4; ++h) {
            u32 kA = ks[h] & 0xFFFFu, kB = ks[h] >> 16;
            u32 tA = trs[h] & 0xFFFFu, tB = trs[h] >> 16;
            int rA = rws[h], rB = rws[h] + 1, cc = cls[h];
            if (kA >= tA) append(lists, cnts, rA, (kA << 16) | (u32)cc);
            if (kB >= tB) append(lists, cnts, rB, (kB << 16) | (u32)cc);
            if (!diag) {
                u32 tc = tcs[h];
                if (kA >= tc) append(lists, cnts, cc, (kA << 16) | (u32)rA);
                if (kB >= tc) append(lists, cnts, cc, (kB << 16) | (u32)rB);
            }
        }
    }
}

// ---------------- topk: exact top-20 + BCE from per-row candidate list ------
__global__ __launch_bounds__(256) void k_topk(const u32* __restrict__ lists,
                                              const u32* __restrict__ cnts,
                                              const int* __restrict__ labels,
                                              float* __restrict__ partials) {
    int lane = threadIdx.x & 63;
    int wv   = threadIdx.x >> 6;
    int row  = blockIdx.x * 4 + wv;
    u32 cnt = min(cnts[row], (u32)NSURV);
    const u32* L = lists + (size_t)row * NSURV;
    int mylab = labels[row];
    float loss = 0.0f;

    if (cnt <= 64u) {
        // fast path: one survivor per lane; V20 bsearch = 16 ballots
        u32 gg  = ((u32)lane < cnt) ? L[lane] : 0u;
        u32 key = gg >> 16;
        u32 V = 0;
        #pragma unroll
        for (int b = 15; b >= 0; --b) {
            u32 cand = V | (1u << b);
            if (__popcll(__ballot(key >= cand)) >= KSEL) V = cand;
        }
        int cgt  = __popcll(__ballot(key > V));
        int ceq  = __popcll(__ballot(gg != 0 && key == V));
        int need = KSEL - cgt;
        bool incl;
        if (ceq == need) {
            incl = (gg != 0) && (key >= V);
        } else {
            // more ties than slots: take `need` largest cols among ties
            u32 col = gg & 0xFFFFu;
            bool tie = (gg != 0) && (key == V);
            u32 Cv = 0;
            #pragma unroll
            for (int b = 15; b >= 0; --b) {
                u32 cand2 = Cv | (1u << b);
                if (__popcll(__ballot(tie && col >= cand2)) >= need) Cv = cand2;
            }
            incl = (key > V) || (tie && col >= Cv);   // cols unique -> exact
        }
        if (incl) {
            u32 col = gg & 0xFFFFu;
            u32 raw = (key & 0x8000u) ? (key ^ 0x8000u) : (key ^ 0xFFFFu);
            float v = __uint_as_float(raw << 16);
            float p = (v + 1.0f) * 0.5f;
            bool tm = (labels[col] == mylab);
            loss -= tm ? fmaxf(logf(p), -100.0f) : fmaxf(log1pf(-p), -100.0f);
        }
    } else {
        // fallback (rare): up to 6 survivors per lane
        u32 g[6];
        #pragma unroll
        for (int j = 0; j < 6; ++j) {
            u32 idx = (u32)lane + (u32)j * 64u;
            g[j] = (idx < cnt) ? L[idx] : 0u;
        }
        u32 V = 0;
        #pragma unroll
        for (int b = 15; b >= 0; --b) {
            u32 cand = V | (1u << b);
            int c = 0;
            #pragma unroll
            for (int j = 0; j < 6; ++j)
                c += __popcll(__ballot((g[j] >> 16) >= cand));
            if (c >= KSEL) V = cand;
        }
        int cgt = 0, ceq = 0;
        #pragma unroll
        for (int j = 0; j < 6; ++j) {
            cgt += __popcll(__ballot(g[j] != 0 && (g[j] >> 16) > V));
            ceq += __popcll(__ballot(g[j] != 0 && (g[j] >> 16) == V));
        }
        int need = KSEL - cgt;
        bool all_ties = (ceq == need);
        #pragma unroll
        for (int j = 0; j < 6; ++j) {
            u32 key = g[j] >> 16, col = g[j] & 0xFFFFu;
            if (g[j] != 0 && (key > V || (all_ties && key == V))) {
                u32 raw = (key & 0x8000u) ? (key ^ 0x8000u) : (key ^ 0xFFFFu);
                float v = __uint_as_float(raw << 16);
                float p = (v + 1.0f) * 0.5f;
                bool tm = (labels[col] == mylab);
                loss -= tm ? fmaxf(logf(p), -100.0f) : fmaxf(log1pf(-p), -100.0f);
            }
        }
        if (!all_ties) {
            for (int r = 0; r < need; ++r) {
                u32 best = 0;
                #pragma unroll
                for (int j = 0; j < 6; ++j) {
                    u32 c2 = (g[j] != 0 && (g[j] >> 16) == V) ? ((g[j] & 0xFFFFu) + 1u) : 0u;
                    best = max(best, c2);
                }
                #pragma unroll
                for (int off = 32; off; off >>= 1) best = max(best, (u32)__shfl_xor((int)best, off));
                #pragma unroll
                for (int j = 0; j < 6; ++j) {
                    if (g[j] != 0 && (g[j] >> 16) == V && ((g[j] & 0xFFFFu) + 1u) == best) {
                        u32 col = g[j] & 0xFFFFu;
                        u32 raw = (V & 0x8000u) ? (V ^ 0x8000u) : (V ^ 0xFFFFu);
                        float v = __uint_as_float(raw << 16);
                        float p = (v + 1.0f) * 0.5f;
                        bool tm = (labels[col] == mylab);
                        loss -= tm ? fmaxf(logf(p), -100.0f) : fmaxf(log1pf(-p), -100.0f);
                        g[j] = 0;
                    }
                }
            }
        }
    }

    #pragma unroll
    for (int off = 32; off; off >>= 1) loss += __shfl_xor(loss, off);
    if (lane == 0) partials[row] = loss;
}

__global__ __launch_bounds__(256) void k_final(const float* __restrict__ partials,
                                               float* __restrict__ out) {
    __shared__ float s[4];
    int tid = threadIdx.x, lane = tid & 63, wvi = tid >> 6;
    const float4* p4 = (const float4*)partials;
    float sum = 0.0f;
    #pragma unroll
    for (int i = 0; i < 8; ++i) {
        float4 v = p4[tid + i * 256];
        sum += v.x + v.y + v.z + v.w;
    }
    #pragma unroll
    for (int off = 32; off; off >>= 1) sum += __shfl_xor(sum, off);
    if (lane == 0) s[wvi] = sum;
    __syncthreads();
    if (tid == 0) out[0] = (s[0] + s[1] + s[2] + s[3]) * (1.0f / (float)(NROWS * KSEL));
}

extern "C" void kernel_launch(void* const* d_in, const int* in_sizes, int n_in,
                              void* d_out, int out_size, void* d_ws, size_t ws_size,
                              hipStream_t stream) {
    const float* batch  = (const float*)d_in[0];
    const int*   labels = (const int*)d_in[1];

    ushort* xn = (ushort*)d_ws;                 // 8 MB
    ushort* C  = xn + (size_t)NROWS * DIM;      // 2080 tiles x 32 KB = 66.5 MB

    // Scratch carved from the batch input buffer (16 MB), all written only
    // after k_norm has fully consumed batch (stream-ordered):
    // [0,2M) M digest | [2M,+16K) T | [+64K,+32K) cnts | [+128K,+32K) partials
    // [4M,16M) lists (8192 rows x 384 x u32)
    char* scr = (char*)d_in[0];
    ushort* M        = (ushort*)scr;
    ushort* T        = (ushort*)(scr + (2u << 20));
    u32*    cnts     = (u32*)  (scr + (2u << 20) + (64u << 10));
    float*  partials = (float*)(scr + (2u << 20) + (128u << 10));
    u32*    lists    = (u32*)  (scr + (4u << 20));

    k_norm<<<NROWS / 4, 256, 0, stream>>>(batch, xn);
    hipMemsetAsync(cnts, 0, NROWS * sizeof(u32), stream);
    k_gemm  <<<NTRI,      256, 0, stream>>>(xn, C, M);
    k_thresh<<<NROWS / 4, 256, 0, stream>>>(M, T);
    k_scan  <<<NTRI,      256, 0, stream>>>(C, T, lists, cnts);
    k_topk  <<<NROWS / 4, 256, 0, stream>>>(lists, cnts, labels, partials);
    k_final <<<1,         256, 0, stream>>>(partials, (float*)d_out);
}